// Round 1
// baseline (508.974 us; speedup 1.0000x reference)
//
#include <hip/hip_runtime.h>

typedef __attribute__((ext_vector_type(8))) __bf16 bf16x8;
typedef __attribute__((ext_vector_type(4))) __bf16 bf16x4;
typedef __attribute__((ext_vector_type(4))) float f32x4;
typedef __attribute__((ext_vector_type(8))) unsigned short u16x8;
typedef __attribute__((ext_vector_type(4))) unsigned short u16x4;

#define MFMA16(a, b, c) __builtin_amdgcn_mfma_f32_16x16x32_bf16((a), (b), (c), 0, 0, 0)

__device__ __forceinline__ unsigned short f2bf(float f) {
    unsigned int u = __float_as_uint(f);
    unsigned int r = (u + 0x7FFFu + ((u >> 16) & 1u)) >> 16;
    return (unsigned short)r;
}

// ---------------- fp32 -> bf16 contiguous convert ----------------
__global__ __launch_bounds__(256) void k_convert(const float* __restrict__ in,
                                                 unsigned short* __restrict__ out, int n4) {
    int i = blockIdx.x * 256 + threadIdx.x;
    if (i >= n4) return;
    const float4 v = ((const float4*)in)[i];
    u16x4 o = { f2bf(v.x), f2bf(v.y), f2bf(v.z), f2bf(v.w) };
    ((u16x4*)out)[i] = o;
}

// ---------------- fp32 [R][C] -> bf16 transposed [C][R] ----------------
__global__ __launch_bounds__(256) void k_transpose(const float* __restrict__ in,
                                                   unsigned short* __restrict__ out,
                                                   int R, int C) {
    __shared__ float tile[32][33];
    const int tx = threadIdx.x & 31, ty = threadIdx.x >> 5;
    const int c0 = blockIdx.x * 32, r0 = blockIdx.y * 32;
#pragma unroll
    for (int i = 0; i < 4; ++i)
        tile[ty + i * 8][tx] = in[(size_t)(r0 + ty + i * 8) * C + c0 + tx];
    __syncthreads();
#pragma unroll
    for (int i = 0; i < 4; ++i)
        out[(size_t)(c0 + ty + i * 8) * R + r0 + tx] = f2bf(tile[tx][ty + i * 8]);
}

// ---------------- bf16 GEMM: C[M][N] = alpha * A[M][K] @ Bt[N][K]^T ----------------
// m97 structure: 128x128 tile, BK=32, 4 waves, 4x4 16x16x32 MFMAs per wave.
template <int OUT_BF16>
__global__ __launch_bounds__(256) void k_gemm_bt(const unsigned short* __restrict__ A,
                                                 const unsigned short* __restrict__ B,
                                                 void* __restrict__ Cv,
                                                 int M, int N, int K, float alpha) {
    __shared__ alignas(16) unsigned short As[128 * 32];
    __shared__ alignas(16) unsigned short Bs[128 * 32];
    const int tid = threadIdx.x;
    const int wave = tid >> 6;
    const int lane = tid & 63;
    const int l16 = lane & 15;
    const int quad = lane >> 4;
    const int bm = blockIdx.y * 128;
    const int bn = blockIdx.x * 128;
    const int wm = (wave >> 1) * 64;
    const int wn = (wave & 1) * 64;

    const f32x4 fzero = {0.f, 0.f, 0.f, 0.f};
    f32x4 acc[4][4];
#pragma unroll
    for (int i = 0; i < 4; ++i)
#pragma unroll
        for (int j = 0; j < 4; ++j) acc[i][j] = fzero;

    auto AsL = (__attribute__((address_space(3))) unsigned short*)As;
    auto BsL = (__attribute__((address_space(3))) unsigned short*)Bs;

    const int c0 = wave * 128 + lane;  // chunk id; chunk = 8 elems; 512 chunks per tile

    for (int kt = 0; kt < K; kt += 32) {
        __syncthreads();
#pragma unroll
        for (int j = 0; j < 2; ++j) {
            const int c = c0 + j * 64;
            __builtin_amdgcn_global_load_lds(
                (const __attribute__((address_space(1))) void*)(A + (size_t)(bm + (c >> 2)) * K + kt + (c & 3) * 8),
                (__attribute__((address_space(3))) void*)(AsL + c * 8), 16, 0, 0);
            __builtin_amdgcn_global_load_lds(
                (const __attribute__((address_space(1))) void*)(B + (size_t)(bn + (c >> 2)) * K + kt + (c & 3) * 8),
                (__attribute__((address_space(3))) void*)(BsL + c * 8), 16, 0, 0);
        }
        __syncthreads();

        bf16x8 af[4], bfr[4];
#pragma unroll
        for (int mt = 0; mt < 4; ++mt)
            af[mt] = *(const bf16x8*)(As + (wm + mt * 16 + l16) * 32 + quad * 8);
#pragma unroll
        for (int nt = 0; nt < 4; ++nt)
            bfr[nt] = *(const bf16x8*)(Bs + (wn + nt * 16 + l16) * 32 + quad * 8);
#pragma unroll
        for (int mt = 0; mt < 4; ++mt)
#pragma unroll
            for (int nt = 0; nt < 4; ++nt)
                acc[mt][nt] = MFMA16(af[mt], bfr[nt], acc[mt][nt]);
    }

#pragma unroll
    for (int mt = 0; mt < 4; ++mt)
#pragma unroll
        for (int nt = 0; nt < 4; ++nt)
#pragma unroll
            for (int r = 0; r < 4; ++r) {
                const int row = bm + wm + mt * 16 + quad * 4 + r;
                const int col = bn + wn + nt * 16 + l16;
                const float v = acc[mt][nt][r] * alpha;
                if (OUT_BF16)
                    ((unsigned short*)Cv)[(size_t)row * N + col] = f2bf(v);
                else
                    ((float*)Cv)[(size_t)row * N + col] = v;
            }
}

// ---------------- flash attention (K == V == kv latent heads) ----------------
// grid: (32 q-tiles of 64 rows, 32 b*h). block 256 = 4 waves; wave owns 16 q-rows.
#define KSTR 136  // Ks row stride (bf16 elems), 272B: 16B-aligned, conflict-free b128
#define VSTR 68   // Vt row stride, 136B: 8B-aligned -> b64 reads
#define PSTR 72   // P row stride, 144B: 16B-aligned b128 reads

__global__ __launch_bounds__(256) void k_attn(const unsigned short* __restrict__ Q,
                                              const unsigned short* __restrict__ KV,
                                              unsigned short* __restrict__ O) {
    __shared__ alignas(16) unsigned short Ks[64 * KSTR];      // 17408 B  K row-major
    __shared__ alignas(16) unsigned short Vt[128 * VSTR];     // 17408 B  K transposed
    __shared__ alignas(16) unsigned short Ps[4 * 16 * PSTR];  // 9216 B   P per wave

    const int tid = threadIdx.x;
    const int wave = tid >> 6, lane = tid & 63;
    const int l16 = lane & 15, quad = lane >> 4;
    const int qt = blockIdx.x;
    const int bh = blockIdx.y;
    const size_t tokbase = (size_t)(bh >> 4) * 2048;
    const int hcol = (bh & 15) * 128;

    // Q A-fragments for this wave's 16 q-rows (held in registers for whole kernel)
    bf16x8 qf[4];
    {
        const unsigned short* qp =
            Q + (tokbase + qt * 64 + wave * 16 + l16) * 2048 + hcol + quad * 8;
#pragma unroll
        for (int ks = 0; ks < 4; ++ks) qf[ks] = *(const bf16x8*)(qp + ks * 32);
    }

    const f32x4 fzero = {0.f, 0.f, 0.f, 0.f};
    f32x4 o_acc[8];
#pragma unroll
    for (int t = 0; t < 8; ++t) o_acc[t] = fzero;
    float m_i[4], l_i[4];
#pragma unroll
    for (int r = 0; r < 4; ++r) { m_i[r] = -3.0e38f; l_i[r] = 0.f; }

    const int sm = tid & 15;   // staging d-chunk (8 elems)
    const int srr = tid >> 4;  // staging row selector

    unsigned short* Pw = Ps + wave * 16 * PSTR;

    for (int kt = 0; kt < 32; ++kt) {
        __syncthreads();
        // ---- stage K tile (64 x 128): Ks row-major + Vt transposed (xor-swizzled rows)
#pragma unroll
        for (int p = 0; p < 4; ++p) {
            const int r = p * 16 + (srr ^ sm);
            const unsigned short* src = KV + (tokbase + kt * 64 + r) * 2048 + hcol + sm * 8;
            u16x8 v = *(const u16x8*)src;
            *(u16x8*)(Ks + r * KSTR + sm * 8) = v;
#pragma unroll
            for (int i = 0; i < 8; ++i) Vt[(sm * 8 + i) * VSTR + r] = v[i];
        }
        __syncthreads();

        // ---- S = Q @ K^T  (16 q-rows x 64 kr per wave)
        f32x4 s[4];
#pragma unroll
        for (int nt = 0; nt < 4; ++nt) {
            f32x4 z = fzero;
#pragma unroll
            for (int ks = 0; ks < 4; ++ks) {
                bf16x8 kf = *(const bf16x8*)(Ks + (nt * 16 + l16) * KSTR + ks * 32 + quad * 8);
                z = MFMA16(qf[ks], kf, z);
            }
            s[nt] = z;
        }

        // ---- online softmax (row = quad*4+r, cols spread over l16 x nt)
        float alpha[4];
#pragma unroll
        for (int r = 0; r < 4; ++r) {
            float v = fmaxf(fmaxf(s[0][r], s[1][r]), fmaxf(s[2][r], s[3][r]));
            v = fmaxf(v, __shfl_xor(v, 1));
            v = fmaxf(v, __shfl_xor(v, 2));
            v = fmaxf(v, __shfl_xor(v, 4));
            v = fmaxf(v, __shfl_xor(v, 8));
            const float mnew = fmaxf(m_i[r], v);
            alpha[r] = __expf(m_i[r] - mnew);
            m_i[r] = mnew;
        }
        float rs[4] = {0.f, 0.f, 0.f, 0.f};
#pragma unroll
        for (int nt = 0; nt < 4; ++nt)
#pragma unroll
            for (int r = 0; r < 4; ++r) {
                const float p = __expf(s[nt][r] - m_i[r]);
                rs[r] += p;
                Pw[(quad * 4 + r) * PSTR + nt * 16 + l16] = f2bf(p);
            }
#pragma unroll
        for (int r = 0; r < 4; ++r) {
            float v = rs[r];
            v += __shfl_xor(v, 1);
            v += __shfl_xor(v, 2);
            v += __shfl_xor(v, 4);
            v += __shfl_xor(v, 8);
            l_i[r] = l_i[r] * alpha[r] + v;
        }
#pragma unroll
        for (int t = 0; t < 8; ++t)
#pragma unroll
            for (int r = 0; r < 4; ++r) o_acc[t][r] *= alpha[r];

        __syncthreads();  // P LDS writes drained+visible before A-frag reads

        // ---- O += P @ V
#pragma unroll
        for (int ks = 0; ks < 2; ++ks) {
            const bf16x8 pf = *(const bf16x8*)(Pw + l16 * PSTR + ks * 32 + quad * 8);
#pragma unroll
            for (int t = 0; t < 8; ++t) {
                const unsigned short* vp = Vt + (t * 16 + l16) * VSTR + ks * 32 + quad * 8;
                bf16x4 lo = *(const bf16x4*)vp;
                bf16x4 hi = *(const bf16x4*)(vp + 4);
                bf16x8 vf = __builtin_shufflevector(lo, hi, 0, 1, 2, 3, 4, 5, 6, 7);
                o_acc[t] = MFMA16(pf, vf, o_acc[t]);
            }
        }
    }

    // ---- epilogue: divide by l, write bf16
#pragma unroll
    for (int r = 0; r < 4; ++r) {
        const float inv = 1.0f / l_i[r];
        unsigned short* dst =
            O + (tokbase + qt * 64 + wave * 16 + quad * 4 + r) * 2048 + hcol;
#pragma unroll
        for (int t = 0; t < 8; ++t) dst[t * 16 + l16] = f2bf(o_acc[t][r] * inv);
    }
}

// ---------------- host launcher ----------------
extern "C" void kernel_launch(void* const* d_in, const int* in_sizes, int n_in,
                              void* d_out, int out_size, void* d_ws, size_t ws_size,
                              hipStream_t stream) {
    const float* x = (const float*)d_in[0];
    const float* W_q = (const float*)d_in[1];
    const float* W_kvd = (const float*)d_in[2];
    const float* W_kvu = (const float*)d_in[3];
    const float* W_o = (const float*)d_in[4];

    char* w = (char*)d_ws;
    unsigned short* xb = (unsigned short*)w;      w += (size_t)4096 * 2048 * 2;
    unsigned short* Wq_t = (unsigned short*)w;    w += (size_t)2048 * 2048 * 2;
    unsigned short* Wkvd_t = (unsigned short*)w;  w += (size_t)512 * 2048 * 2;
    unsigned short* Wkvu_t = (unsigned short*)w;  w += (size_t)2048 * 512 * 2;
    unsigned short* Wo_t = (unsigned short*)w;    w += (size_t)2048 * 2048 * 2;
    unsigned short* qb = (unsigned short*)w;      w += (size_t)4096 * 2048 * 2;
    unsigned short* lat = (unsigned short*)w;     w += (size_t)4096 * 512 * 2;
    unsigned short* kvb = (unsigned short*)w;     w += (size_t)4096 * 2048 * 2;
    unsigned short* attn = xb;  // xb dead after the latent GEMM; alias to save ws

    // bf16 conversions / weight transposes to [N][K]
    k_convert<<<8192, 256, 0, stream>>>(x, xb, 2097152);
    k_transpose<<<dim3(64, 64), 256, 0, stream>>>(W_q, Wq_t, 2048, 2048);
    k_transpose<<<dim3(16, 64), 256, 0, stream>>>(W_kvd, Wkvd_t, 2048, 512);
    k_transpose<<<dim3(64, 16), 256, 0, stream>>>(W_kvu, Wkvu_t, 512, 2048);
    k_transpose<<<dim3(64, 64), 256, 0, stream>>>(W_o, Wo_t, 2048, 2048);

    // q = (x @ W_q) * 1/sqrt(128)   [softmax scale folded in]
    k_gemm_bt<1><<<dim3(16, 32), 256, 0, stream>>>(xb, Wq_t, qb, 4096, 2048, 2048,
                                                   0.08838834764831845f);
    // latent = x @ W_kv_down
    k_gemm_bt<1><<<dim3(4, 32), 256, 0, stream>>>(xb, Wkvd_t, lat, 4096, 512, 2048, 1.0f);
    // kv = latent @ W_kv_up
    k_gemm_bt<1><<<dim3(16, 32), 256, 0, stream>>>(lat, Wkvu_t, kvb, 4096, 2048, 512, 1.0f);
    // flash attention
    k_attn<<<dim3(32, 32), 256, 0, stream>>>(qb, kvb, attn);
    // out = attn @ W_o  (fp32 output)
    k_gemm_bt<0><<<dim3(16, 32), 256, 0, stream>>>(attn, Wo_t, d_out, 4096, 2048, 2048, 1.0f);
}

// Round 2
// 485.158 us; speedup vs baseline: 1.0491x; 1.0491x over previous
//
#include <hip/hip_runtime.h>

typedef __attribute__((ext_vector_type(8))) __bf16 bf16x8;
typedef __attribute__((ext_vector_type(4))) float f32x4;
typedef __attribute__((ext_vector_type(8))) unsigned short u16x8;
typedef __attribute__((ext_vector_type(4))) unsigned short u16x4;

#define MFMA16(a, b, c) __builtin_amdgcn_mfma_f32_16x16x32_bf16((a), (b), (c), 0, 0, 0)

__device__ __forceinline__ unsigned short f2bf(float f) {
    unsigned int u = __float_as_uint(f);
    unsigned int r = (u + 0x7FFFu + ((u >> 16) & 1u)) >> 16;
    return (unsigned short)r;
}

// ---------------- fp32 -> bf16 contiguous convert ----------------
__global__ __launch_bounds__(256) void k_convert(const float* __restrict__ in,
                                                 unsigned short* __restrict__ out, int n4) {
    int i = blockIdx.x * 256 + threadIdx.x;
    if (i >= n4) return;
    const float4 v = ((const float4*)in)[i];
    u16x4 o = { f2bf(v.x), f2bf(v.y), f2bf(v.z), f2bf(v.w) };
    ((u16x4*)out)[i] = o;
}

// ---------------- fp32 [R][C] -> bf16 transposed [C][R] ----------------
__global__ __launch_bounds__(256) void k_transpose(const float* __restrict__ in,
                                                   unsigned short* __restrict__ out,
                                                   int R, int C) {
    __shared__ float tile[32][33];
    const int tx = threadIdx.x & 31, ty = threadIdx.x >> 5;
    const int c0 = blockIdx.x * 32, r0 = blockIdx.y * 32;
#pragma unroll
    for (int i = 0; i < 4; ++i)
        tile[ty + i * 8][tx] = in[(size_t)(r0 + ty + i * 8) * C + c0 + tx];
    __syncthreads();
#pragma unroll
    for (int i = 0; i < 4; ++i)
        out[(size_t)(c0 + ty + i * 8) * R + r0 + tx] = f2bf(tile[tx][ty + i * 8]);
}

// ---------------- bf16 GEMM: C[M][N] = alpha * A[M][K] @ Bt[N][K]^T ----------------
// OUT_MODE: 0 = fp32 C, 1 = bf16 C, 2 = bf16 C + transposed bf16 copy Ct
//   (Ct layout: [row>>11][col>>7][col&127][row&2047] -- per-(batch,head) d-major)
template <int OUT_MODE>
__global__ __launch_bounds__(256) void k_gemm_bt(const unsigned short* __restrict__ A,
                                                 const unsigned short* __restrict__ B,
                                                 void* __restrict__ Cv,
                                                 unsigned short* __restrict__ Ct,
                                                 int M, int N, int K, float alpha) {
    __shared__ alignas(16) unsigned short As[128 * 32];
    __shared__ alignas(16) unsigned short Bs[128 * 32];
    const int tid = threadIdx.x;
    const int wave = tid >> 6;
    const int lane = tid & 63;
    const int l16 = lane & 15;
    const int quad = lane >> 4;
    const int bm = blockIdx.y * 128;
    const int bn = blockIdx.x * 128;
    const int wm = (wave >> 1) * 64;
    const int wn = (wave & 1) * 64;

    const f32x4 fzero = {0.f, 0.f, 0.f, 0.f};
    f32x4 acc[4][4];
#pragma unroll
    for (int i = 0; i < 4; ++i)
#pragma unroll
        for (int j = 0; j < 4; ++j) acc[i][j] = fzero;

    auto AsL = (__attribute__((address_space(3))) unsigned short*)As;
    auto BsL = (__attribute__((address_space(3))) unsigned short*)Bs;

    const int c0 = wave * 128 + lane;  // chunk id; chunk = 8 elems; 512 chunks per tile

    for (int kt = 0; kt < K; kt += 32) {
        __syncthreads();
#pragma unroll
        for (int j = 0; j < 2; ++j) {
            const int c = c0 + j * 64;
            __builtin_amdgcn_global_load_lds(
                (const __attribute__((address_space(1))) void*)(A + (size_t)(bm + (c >> 2)) * K + kt + (c & 3) * 8),
                (__attribute__((address_space(3))) void*)(AsL + c * 8), 16, 0, 0);
            __builtin_amdgcn_global_load_lds(
                (const __attribute__((address_space(1))) void*)(B + (size_t)(bn + (c >> 2)) * K + kt + (c & 3) * 8),
                (__attribute__((address_space(3))) void*)(BsL + c * 8), 16, 0, 0);
        }
        __syncthreads();

        bf16x8 af[4], bfr[4];
#pragma unroll
        for (int mt = 0; mt < 4; ++mt)
            af[mt] = *(const bf16x8*)(As + (wm + mt * 16 + l16) * 32 + quad * 8);
#pragma unroll
        for (int nt = 0; nt < 4; ++nt)
            bfr[nt] = *(const bf16x8*)(Bs + (wn + nt * 16 + l16) * 32 + quad * 8);
#pragma unroll
        for (int mt = 0; mt < 4; ++mt)
#pragma unroll
            for (int nt = 0; nt < 4; ++nt)
                acc[mt][nt] = MFMA16(af[mt], bfr[nt], acc[mt][nt]);
    }

#pragma unroll
    for (int mt = 0; mt < 4; ++mt)
#pragma unroll
        for (int nt = 0; nt < 4; ++nt) {
            const int row0 = bm + wm + mt * 16 + quad * 4;
            const int col = bn + wn + nt * 16 + l16;
            u16x4 pk;
#pragma unroll
            for (int r = 0; r < 4; ++r) {
                const float v = acc[mt][nt][r] * alpha;
                if (OUT_MODE == 0) {
                    ((float*)Cv)[(size_t)(row0 + r) * N + col] = v;
                } else {
                    const unsigned short b = f2bf(v);
                    ((unsigned short*)Cv)[(size_t)(row0 + r) * N + col] = b;
                    pk[r] = b;
                }
            }
            if (OUT_MODE == 2) {
                const size_t ti =
                    ((size_t)((row0 >> 11) * (N >> 7) + (col >> 7)) * 128 + (col & 127)) * 2048 +
                    (row0 & 2047);
                *(u16x4*)(Ct + ti) = pk;
            }
        }
}

// ---------------- flash attention (K == V == kv latent heads) ----------------
// grid: (32 q-tiles of 64 rows, 32 b*h). block 256 = 4 waves; wave owns 16 q-rows.
// LDS = 16K (Ks) + 16K (Vt) + 8K (Ps) = 40960 B -> 4 blocks/CU.
// All LDS layouts xor-swizzled on 16B chunks: conflict-free b128 writes AND reads.
// Writes output IN-PLACE over Q (each block reads exactly the rows it writes,
// into registers, before any store).
__global__ __launch_bounds__(256) void k_attn(const unsigned short* __restrict__ Q,
                                              const unsigned short* __restrict__ KV,
                                              const unsigned short* __restrict__ KVT,
                                              unsigned short* __restrict__ O) {
    __shared__ alignas(16) unsigned short Ks[64 * 128];  // [kr][d], chunk-swizzled
    __shared__ alignas(16) unsigned short Vt[128 * 64];  // [d][kr], chunk-swizzled
    __shared__ alignas(16) unsigned short Ps[4 * 16 * 64];  // per-wave P, swizzled

    const int tid = threadIdx.x;
    const int wave = tid >> 6, lane = tid & 63;
    const int l16 = lane & 15, quad = lane >> 4;
    const int l8 = l16 & 7;
    const int qt = blockIdx.x;
    const int bh = blockIdx.y;
    const size_t tokbase = (size_t)(bh >> 4) * 2048;
    const int hcol = (bh & 15) * 128;
    const unsigned short* kvt_head = KVT + (size_t)bh * (128 * 2048);

    // Q A-fragments (16 q-rows per wave), held in registers for the whole kernel
    bf16x8 qf[4];
    {
        const unsigned short* qp =
            Q + (tokbase + qt * 64 + wave * 16 + l16) * 2048 + hcol + quad * 8;
#pragma unroll
        for (int ks = 0; ks < 4; ++ks) qf[ks] = *(const bf16x8*)(qp + ks * 32);
    }

    const f32x4 fzero = {0.f, 0.f, 0.f, 0.f};
    f32x4 o_acc[8];
#pragma unroll
    for (int t = 0; t < 8; ++t) o_acc[t] = fzero;
    float m_i[4], l_i[4];
#pragma unroll
    for (int r = 0; r < 4; ++r) { m_i[r] = -3.0e38f; l_i[r] = 0.f; }

    // staging index split
    const int krow = tid >> 4, kchunk = tid & 15;  // Ks: 16 rows x 16 chunks per pass
    const int vrow = tid >> 3, vchunk = tid & 7;   // Vt: 32 rows x 8 chunks per pass

    unsigned short* Pw = Ps + wave * (16 * 64);

    for (int kt = 0; kt < 32; ++kt) {
        __syncthreads();
        // ---- stage K tile row-major [64][128] from kvb (swizzled b128 writes)
#pragma unroll
        for (int p = 0; p < 4; ++p) {
            const int r = p * 16 + krow;
            const u16x8 v =
                *(const u16x8*)(KV + (tokbase + kt * 64 + r) * 2048 + hcol + kchunk * 8);
            const int sw = (kchunk & 8) | ((kchunk & 7) ^ (krow & 7));
            *(u16x8*)(Ks + r * 128 + sw * 8) = v;
        }
        // ---- stage V^T tile [128][64] from kvT (coalesced reads, swizzled writes)
#pragma unroll
        for (int p = 0; p < 4; ++p) {
            const int d = p * 32 + vrow;
            const u16x8 v = *(const u16x8*)(kvt_head + d * 2048 + kt * 64 + vchunk * 8);
            const int sw = vchunk ^ (vrow & 7);
            *(u16x8*)(Vt + d * 64 + sw * 8) = v;
        }
        __syncthreads();

        // ---- S = Q @ K^T  (16 q-rows x 64 kr per wave)
        f32x4 s[4];
#pragma unroll
        for (int nt = 0; nt < 4; ++nt) {
            f32x4 z = fzero;
#pragma unroll
            for (int ks = 0; ks < 4; ++ks) {
                const int chunk = ks * 4 + quad;
                const int sw = (chunk & 8) | ((chunk & 7) ^ l8);
                const bf16x8 kf = *(const bf16x8*)(Ks + (nt * 16 + l16) * 128 + sw * 8);
                z = MFMA16(qf[ks], kf, z);
            }
            s[nt] = z;
        }

        // ---- online softmax (row = quad*4+r, cols spread over l16 x nt)
        float alpha[4];
#pragma unroll
        for (int r = 0; r < 4; ++r) {
            float v = fmaxf(fmaxf(s[0][r], s[1][r]), fmaxf(s[2][r], s[3][r]));
            v = fmaxf(v, __shfl_xor(v, 1));
            v = fmaxf(v, __shfl_xor(v, 2));
            v = fmaxf(v, __shfl_xor(v, 4));
            v = fmaxf(v, __shfl_xor(v, 8));
            const float mnew = fmaxf(m_i[r], v);
            alpha[r] = __expf(m_i[r] - mnew);
            m_i[r] = mnew;
        }
        float rs[4] = {0.f, 0.f, 0.f, 0.f};
#pragma unroll
        for (int nt = 0; nt < 4; ++nt) {
            const int chunk = nt * 2 + (l16 >> 3);
#pragma unroll
            for (int r = 0; r < 4; ++r) {
                const int qp = quad * 4 + r;
                const float p = __expf(s[nt][r] - m_i[r]);
                rs[r] += p;
                Pw[qp * 64 + (chunk ^ (qp & 7)) * 8 + l8] = f2bf(p);
            }
        }
#pragma unroll
        for (int r = 0; r < 4; ++r) {
            float v = rs[r];
            v += __shfl_xor(v, 1);
            v += __shfl_xor(v, 2);
            v += __shfl_xor(v, 4);
            v += __shfl_xor(v, 8);
            l_i[r] = l_i[r] * alpha[r] + v;
        }
#pragma unroll
        for (int t = 0; t < 8; ++t)
#pragma unroll
            for (int r = 0; r < 4; ++r) o_acc[t][r] *= alpha[r];

        __syncthreads();  // P visible before A-frag reads

        // ---- O += P @ V
#pragma unroll
        for (int ks = 0; ks < 2; ++ks) {
            const int pc = ks * 4 + quad;
            const bf16x8 pf = *(const bf16x8*)(Pw + l16 * 64 + (pc ^ l8) * 8);
            const int vsw = (pc ^ l8) * 8;
#pragma unroll
            for (int t = 0; t < 8; ++t) {
                const bf16x8 vf = *(const bf16x8*)(Vt + (t * 16 + l16) * 64 + vsw);
                o_acc[t] = MFMA16(pf, vf, o_acc[t]);
            }
        }
    }

    // ---- epilogue: divide by l, write bf16 (in-place over this block's Q rows)
#pragma unroll
    for (int r = 0; r < 4; ++r) {
        const float inv = 1.0f / l_i[r];
        unsigned short* dst =
            O + (tokbase + qt * 64 + wave * 16 + quad * 4 + r) * 2048 + hcol;
#pragma unroll
        for (int t = 0; t < 8; ++t) dst[t * 16 + l16] = f2bf(o_acc[t][r] * inv);
    }
}

// ---------------- host launcher ----------------
extern "C" void kernel_launch(void* const* d_in, const int* in_sizes, int n_in,
                              void* d_out, int out_size, void* d_ws, size_t ws_size,
                              hipStream_t stream) {
    const float* x = (const float*)d_in[0];
    const float* W_q = (const float*)d_in[1];
    const float* W_kvd = (const float*)d_in[2];
    const float* W_kvu = (const float*)d_in[3];
    const float* W_o = (const float*)d_in[4];

    // 72 MB workspace layout (lifetime-packed):
    //   [0,16M)   xb (x bf16; dead after kv-down)  -> reused as kvT
    //   [16,32M)  qb (q; attn writes output in-place here)
    //   [32,48M)  kvb (row-major kv)
    //   [48,56M)  Wo_t
    //   [56,64M)  Wq_t
    //   [64,66M)  Wkvd_t
    //   [66,68M)  Wkvu_t
    //   [68,72M)  lat
    char* w = (char*)d_ws;
    unsigned short* xb = (unsigned short*)(w);
    unsigned short* kvT = xb;  // aliases xb after it's dead
    unsigned short* qb = (unsigned short*)(w + (size_t)16 * 1024 * 1024);
    unsigned short* kvb = (unsigned short*)(w + (size_t)32 * 1024 * 1024);
    unsigned short* Wo_t = (unsigned short*)(w + (size_t)48 * 1024 * 1024);
    unsigned short* Wq_t = (unsigned short*)(w + (size_t)56 * 1024 * 1024);
    unsigned short* Wkvd_t = (unsigned short*)(w + (size_t)64 * 1024 * 1024);
    unsigned short* Wkvu_t = (unsigned short*)(w + (size_t)66 * 1024 * 1024);
    unsigned short* lat = (unsigned short*)(w + (size_t)68 * 1024 * 1024);

    // bf16 conversions / weight transposes to [N][K]
    k_convert<<<8192, 256, 0, stream>>>(x, xb, 2097152);
    k_transpose<<<dim3(64, 64), 256, 0, stream>>>(W_q, Wq_t, 2048, 2048);
    k_transpose<<<dim3(16, 64), 256, 0, stream>>>(W_kvd, Wkvd_t, 2048, 512);
    k_transpose<<<dim3(64, 16), 256, 0, stream>>>(W_kvu, Wkvu_t, 512, 2048);
    k_transpose<<<dim3(64, 64), 256, 0, stream>>>(W_o, Wo_t, 2048, 2048);

    // q = (x @ W_q) * 1/sqrt(128)   [softmax scale folded in]
    k_gemm_bt<1><<<dim3(16, 32), 256, 0, stream>>>(xb, Wq_t, qb, nullptr, 4096, 2048, 2048,
                                                   0.08838834764831845f);
    // latent = x @ W_kv_down
    k_gemm_bt<1><<<dim3(4, 32), 256, 0, stream>>>(xb, Wkvd_t, lat, nullptr, 4096, 512, 2048,
                                                  1.0f);
    // kv = latent @ W_kv_up  (also writes kvT = per-head transposed copy; xb is dead now)
    k_gemm_bt<2><<<dim3(16, 32), 256, 0, stream>>>(lat, Wkvu_t, kvb, kvT, 4096, 2048, 512,
                                                   1.0f);
    // flash attention (output in-place over qb)
    k_attn<<<dim3(32, 32), 256, 0, stream>>>(qb, kvb, kvT, qb);
    // out = attn @ W_o  (fp32 output)
    k_gemm_bt<0><<<dim3(16, 32), 256, 0, stream>>>(qb, Wo_t, d_out, nullptr, 4096, 2048, 2048,
                                                   1.0f);
}

// Round 3
// 395.200 us; speedup vs baseline: 1.2879x; 1.2276x over previous
//
#include <hip/hip_runtime.h>

typedef __attribute__((ext_vector_type(8))) __bf16 bf16x8;
typedef __attribute__((ext_vector_type(4))) float f32x4;
typedef __attribute__((ext_vector_type(8))) unsigned short u16x8;
typedef __attribute__((ext_vector_type(4))) unsigned short u16x4;

#define MFMA16(a, b, c) __builtin_amdgcn_mfma_f32_16x16x32_bf16((a), (b), (c), 0, 0, 0)

__device__ __forceinline__ unsigned short f2bf(float f) {
    unsigned int u = __float_as_uint(f);
    unsigned int r = (u + 0x7FFFu + ((u >> 16) & 1u)) >> 16;
    return (unsigned short)r;
}

// ---------------- fp32 -> bf16 contiguous convert ----------------
__global__ __launch_bounds__(256) void k_convert(const float* __restrict__ in,
                                                 unsigned short* __restrict__ out, int n4) {
    int i = blockIdx.x * 256 + threadIdx.x;
    if (i >= n4) return;
    const float4 v = ((const float4*)in)[i];
    u16x4 o = { f2bf(v.x), f2bf(v.y), f2bf(v.z), f2bf(v.w) };
    ((u16x4*)out)[i] = o;
}

// ---------------- fp32 [R][C] -> bf16 transposed [C][R] ----------------
__global__ __launch_bounds__(256) void k_transpose(const float* __restrict__ in,
                                                   unsigned short* __restrict__ out,
                                                   int R, int C) {
    __shared__ float tile[32][33];
    const int tx = threadIdx.x & 31, ty = threadIdx.x >> 5;
    const int c0 = blockIdx.x * 32, r0 = blockIdx.y * 32;
#pragma unroll
    for (int i = 0; i < 4; ++i)
        tile[ty + i * 8][tx] = in[(size_t)(r0 + ty + i * 8) * C + c0 + tx];
    __syncthreads();
#pragma unroll
    for (int i = 0; i < 4; ++i)
        out[(size_t)(c0 + ty + i * 8) * R + r0 + tx] = f2bf(tile[tx][ty + i * 8]);
}

// ---------------- bf16 GEMM: C[M][N] = alpha * A[M][K] @ Bt[N][K]^T ----------------
// OUT_MODE: 0 = fp32 C, 1 = bf16 C, 2 = bf16 C + transposed bf16 copy Ct
//   (Ct layout: [row>>11][col>>7][col&127][row&2047] -- per-(batch,head) d-major)
template <int OUT_MODE>
__global__ __launch_bounds__(256) void k_gemm_bt(const unsigned short* __restrict__ A,
                                                 const unsigned short* __restrict__ B,
                                                 void* __restrict__ Cv,
                                                 unsigned short* __restrict__ Ct,
                                                 int M, int N, int K, float alpha) {
    __shared__ alignas(16) unsigned short As[128 * 32];
    __shared__ alignas(16) unsigned short Bs[128 * 32];
    const int tid = threadIdx.x;
    const int wave = tid >> 6;
    const int lane = tid & 63;
    const int l16 = lane & 15;
    const int quad = lane >> 4;
    const int bm = blockIdx.y * 128;
    const int bn = blockIdx.x * 128;
    const int wm = (wave >> 1) * 64;
    const int wn = (wave & 1) * 64;

    const f32x4 fzero = {0.f, 0.f, 0.f, 0.f};
    f32x4 acc[4][4];
#pragma unroll
    for (int i = 0; i < 4; ++i)
#pragma unroll
        for (int j = 0; j < 4; ++j) acc[i][j] = fzero;

    auto AsL = (__attribute__((address_space(3))) unsigned short*)As;
    auto BsL = (__attribute__((address_space(3))) unsigned short*)Bs;

    const int c0 = wave * 128 + lane;  // chunk id; chunk = 8 elems; 512 chunks per tile

    for (int kt = 0; kt < K; kt += 32) {
        __syncthreads();
#pragma unroll
        for (int j = 0; j < 2; ++j) {
            const int c = c0 + j * 64;
            __builtin_amdgcn_global_load_lds(
                (const __attribute__((address_space(1))) void*)(A + (size_t)(bm + (c >> 2)) * K + kt + (c & 3) * 8),
                (__attribute__((address_space(3))) void*)(AsL + c * 8), 16, 0, 0);
            __builtin_amdgcn_global_load_lds(
                (const __attribute__((address_space(1))) void*)(B + (size_t)(bn + (c >> 2)) * K + kt + (c & 3) * 8),
                (__attribute__((address_space(3))) void*)(BsL + c * 8), 16, 0, 0);
        }
        __syncthreads();

        bf16x8 af[4], bfr[4];
#pragma unroll
        for (int mt = 0; mt < 4; ++mt)
            af[mt] = *(const bf16x8*)(As + (wm + mt * 16 + l16) * 32 + quad * 8);
#pragma unroll
        for (int nt = 0; nt < 4; ++nt)
            bfr[nt] = *(const bf16x8*)(Bs + (wn + nt * 16 + l16) * 32 + quad * 8);
#pragma unroll
        for (int mt = 0; mt < 4; ++mt)
#pragma unroll
            for (int nt = 0; nt < 4; ++nt)
                acc[mt][nt] = MFMA16(af[mt], bfr[nt], acc[mt][nt]);
    }

#pragma unroll
    for (int mt = 0; mt < 4; ++mt)
#pragma unroll
        for (int nt = 0; nt < 4; ++nt) {
            const int row0 = bm + wm + mt * 16 + quad * 4;
            const int col = bn + wn + nt * 16 + l16;
            u16x4 pk;
#pragma unroll
            for (int r = 0; r < 4; ++r) {
                const float v = acc[mt][nt][r] * alpha;
                if (OUT_MODE == 0) {
                    ((float*)Cv)[(size_t)(row0 + r) * N + col] = v;
                } else {
                    const unsigned short b = f2bf(v);
                    ((unsigned short*)Cv)[(size_t)(row0 + r) * N + col] = b;
                    pk[r] = b;
                }
            }
            if (OUT_MODE == 2) {
                const size_t ti =
                    ((size_t)((row0 >> 11) * (N >> 7) + (col >> 7)) * 128 + (col & 127)) * 2048 +
                    (row0 & 2047);
                *(u16x4*)(Ct + ti) = pk;
            }
        }
}

// ---------------- flash attention, S^T formulation (K == V latent heads) ----------------
// grid: (16 q-tiles of 128 rows, 32 b*h). block 256 = 4 waves; wave owns 32 q-rows
// (2 n-tiles). S^T = K @ Q^T via MFMA(kf, qf): each lane's scores sit on ONE q-row
// (col = l16) -> softmax state is lane-scalar, row-reduce = in-reg tree + 2 shuffles.
// P^T exits in C-layout with 4 consecutive k per reg quad -> packed b64 LDS writes.
// P is PER-WAVE PRIVATE (written and read by the same wave, DS pipe is in-order)
// -> only 2 barriers per ktile (Ks/Vt staging). O^T = V^T @ P^T accumulated in regs.
// LDS: Ks 16K + Vt 16K + Ps 16K = 48K. Writes output IN-PLACE over Q.
__global__ __launch_bounds__(256, 2) void k_attn(const unsigned short* __restrict__ Q,
                                                 const unsigned short* __restrict__ KV,
                                                 const unsigned short* __restrict__ KVT,
                                                 unsigned short* __restrict__ O) {
    __shared__ alignas(16) unsigned short Ks[64 * 128];   // [kr][d], chunk-swizzled
    __shared__ alignas(16) unsigned short Vt[128 * 64];   // [d][kr], chunk-swizzled
    __shared__ alignas(16) unsigned short Ps[4 * 32 * 64];  // per-wave P^T as [q][k]

    const int tid = threadIdx.x;
    const int wave = tid >> 6, lane = tid & 63;
    const int l16 = lane & 15, quad = lane >> 4;
    const int l8 = l16 & 7;
    const int qt = blockIdx.x;
    const int bh = blockIdx.y;
    const size_t tokbase = (size_t)(bh >> 4) * 2048;
    const int hcol = (bh & 15) * 128;
    const unsigned short* kvt_head = KVT + (size_t)bh * (128 * 2048);

    // Q B-frags (identical register contents to A-frags): 2 ntiles x 4 d-chunks
    bf16x8 qf[2][4];
    const int qrow0 = qt * 128 + wave * 32;
#pragma unroll
    for (int nt = 0; nt < 2; ++nt) {
        const unsigned short* qp =
            Q + (tokbase + qrow0 + nt * 16 + l16) * 2048 + hcol + quad * 8;
#pragma unroll
        for (int kd = 0; kd < 4; ++kd) qf[nt][kd] = *(const bf16x8*)(qp + kd * 32);
    }

    const f32x4 fzero = {0.f, 0.f, 0.f, 0.f};
    f32x4 o_acc[8][2];  // O^T[d=dt*16+quad*4+r][q=nt*16+l16]
#pragma unroll
    for (int dt = 0; dt < 8; ++dt)
#pragma unroll
        for (int nt = 0; nt < 2; ++nt) o_acc[dt][nt] = fzero;
    float m_i[2] = {-3.0e38f, -3.0e38f}, l_i[2] = {0.f, 0.f};

    const int krow = tid >> 4, kchunk = tid & 15;  // Ks staging: 16 rows x 16 chunks
    const int vrow = tid >> 3, vchunk = tid & 7;   // Vt staging: 32 rows x 8 chunks

    unsigned short* Pw = Ps + wave * (32 * 64);

    for (int kt = 0; kt < 32; ++kt) {
        __syncthreads();
        // ---- stage K tile [64][128] (swizzled b128 writes)
#pragma unroll
        for (int p = 0; p < 4; ++p) {
            const int r = p * 16 + krow;
            const u16x8 v =
                *(const u16x8*)(KV + (tokbase + kt * 64 + r) * 2048 + hcol + kchunk * 8);
            const int sw = (kchunk & 8) | ((kchunk & 7) ^ (r & 7));
            *(u16x8*)(Ks + r * 128 + sw * 8) = v;
        }
        // ---- stage V^T tile [128][64] (swizzled b128 writes)
#pragma unroll
        for (int p = 0; p < 4; ++p) {
            const int d = p * 32 + vrow;
            const u16x8 v = *(const u16x8*)(kvt_head + d * 2048 + kt * 64 + vchunk * 8);
            const int sw = vchunk ^ (d & 7);
            *(u16x8*)(Vt + d * 64 + sw * 8) = v;
        }
        __syncthreads();

        // ---- S^T = K @ Q^T : st[mt][nt] covers (k=mt*16+quad*4+r, q=nt*16+l16)
        f32x4 st[4][2];
#pragma unroll
        for (int mt = 0; mt < 4; ++mt)
#pragma unroll
            for (int nt = 0; nt < 2; ++nt) st[mt][nt] = fzero;
#pragma unroll
        for (int kd = 0; kd < 4; ++kd)
#pragma unroll
            for (int mt = 0; mt < 4; ++mt) {
                const int c = kd * 4 + quad;
                const int sw = (c & 8) | ((c & 7) ^ l8);
                const bf16x8 kf = *(const bf16x8*)(Ks + (mt * 16 + l16) * 128 + sw * 8);
                st[mt][0] = MFMA16(kf, qf[0][kd], st[mt][0]);
                st[mt][1] = MFMA16(kf, qf[1][kd], st[mt][1]);
            }

        // ---- online softmax (all of a lane's values share q = nt*16+l16)
        float aL[2];
#pragma unroll
        for (int nt = 0; nt < 2; ++nt) {
            float mx = st[0][nt][0];
#pragma unroll
            for (int mt = 0; mt < 4; ++mt)
#pragma unroll
                for (int r = 0; r < 4; ++r) mx = fmaxf(mx, st[mt][nt][r]);
            mx = fmaxf(mx, __shfl_xor(mx, 16));
            mx = fmaxf(mx, __shfl_xor(mx, 32));
            const float mnew = fmaxf(m_i[nt], mx);
            aL[nt] = __expf(m_i[nt] - mnew);
            m_i[nt] = mnew;

            float rs = 0.f;
            unsigned short* prow = Pw + (nt * 16 + l16) * 64;
#pragma unroll
            for (int mt = 0; mt < 4; ++mt) {
                u16x4 pk;
#pragma unroll
                for (int r = 0; r < 4; ++r) {
                    const float p = __expf(st[mt][nt][r] - mnew);
                    rs += p;
                    pk[r] = f2bf(p);
                }
                // k0 = mt*16+quad*4 -> 16B chunk c = mt*2+(quad>>1), 8B half = quad&1
                const int c = mt * 2 + (quad >> 1);
                *(u16x4*)(prow + (c ^ l8) * 8 + (quad & 1) * 4) = pk;
            }
            rs += __shfl_xor(rs, 16);
            rs += __shfl_xor(rs, 32);
            l_i[nt] = l_i[nt] * aL[nt] + rs;
        }
#pragma unroll
        for (int dt = 0; dt < 8; ++dt)
#pragma unroll
            for (int nt = 0; nt < 2; ++nt)
#pragma unroll
                for (int r = 0; r < 4; ++r) o_acc[dt][nt][r] *= aL[nt];

        __builtin_amdgcn_sched_barrier(0);  // keep P writes before P reads

        // ---- O^T += V^T @ P^T (P private to this wave: no block barrier needed)
#pragma unroll
        for (int s = 0; s < 2; ++s) {
            const int c = s * 4 + quad;
            const int sw = (c ^ l8) * 8;
            bf16x8 pfr[2];
#pragma unroll
            for (int nt = 0; nt < 2; ++nt)
                pfr[nt] = *(const bf16x8*)(Pw + (nt * 16 + l16) * 64 + sw);
#pragma unroll
            for (int dt = 0; dt < 8; ++dt) {
                const bf16x8 vf = *(const bf16x8*)(Vt + (dt * 16 + l16) * 64 + sw);
                o_acc[dt][0] = MFMA16(vf, pfr[0], o_acc[dt][0]);
                o_acc[dt][1] = MFMA16(vf, pfr[1], o_acc[dt][1]);
            }
        }
    }

    // ---- epilogue: O^T[d][q] -> O[tok][d], divide by l, packed b64 stores
#pragma unroll
    for (int nt = 0; nt < 2; ++nt) {
        const float inv = 1.0f / l_i[nt];
        unsigned short* dst = O + (tokbase + qrow0 + nt * 16 + l16) * 2048 + hcol;
#pragma unroll
        for (int dt = 0; dt < 8; ++dt) {
            u16x4 pk;
#pragma unroll
            for (int r = 0; r < 4; ++r) pk[r] = f2bf(o_acc[dt][nt][r] * inv);
            *(u16x4*)(dst + dt * 16 + quad * 4) = pk;
        }
    }
}

// ---------------- host launcher ----------------
extern "C" void kernel_launch(void* const* d_in, const int* in_sizes, int n_in,
                              void* d_out, int out_size, void* d_ws, size_t ws_size,
                              hipStream_t stream) {
    const float* x = (const float*)d_in[0];
    const float* W_q = (const float*)d_in[1];
    const float* W_kvd = (const float*)d_in[2];
    const float* W_kvu = (const float*)d_in[3];
    const float* W_o = (const float*)d_in[4];

    // 72 MB workspace layout (lifetime-packed):
    //   [0,16M)   xb (x bf16; dead after kv-down)  -> reused as kvT
    //   [16,32M)  qb (q; attn writes output in-place here)
    //   [32,48M)  kvb (row-major kv)
    //   [48,56M)  Wo_t ; [56,64M) Wq_t ; [64,66M) Wkvd_t ; [66,68M) Wkvu_t ; [68,72M) lat
    char* w = (char*)d_ws;
    unsigned short* xb = (unsigned short*)(w);
    unsigned short* kvT = xb;  // aliases xb after it's dead
    unsigned short* qb = (unsigned short*)(w + (size_t)16 * 1024 * 1024);
    unsigned short* kvb = (unsigned short*)(w + (size_t)32 * 1024 * 1024);
    unsigned short* Wo_t = (unsigned short*)(w + (size_t)48 * 1024 * 1024);
    unsigned short* Wq_t = (unsigned short*)(w + (size_t)56 * 1024 * 1024);
    unsigned short* Wkvd_t = (unsigned short*)(w + (size_t)64 * 1024 * 1024);
    unsigned short* Wkvu_t = (unsigned short*)(w + (size_t)66 * 1024 * 1024);
    unsigned short* lat = (unsigned short*)(w + (size_t)68 * 1024 * 1024);

    // bf16 conversions / weight transposes to [N][K]
    k_convert<<<8192, 256, 0, stream>>>(x, xb, 2097152);
    k_transpose<<<dim3(64, 64), 256, 0, stream>>>(W_q, Wq_t, 2048, 2048);
    k_transpose<<<dim3(16, 64), 256, 0, stream>>>(W_kvd, Wkvd_t, 2048, 512);
    k_transpose<<<dim3(64, 16), 256, 0, stream>>>(W_kvu, Wkvu_t, 512, 2048);
    k_transpose<<<dim3(64, 64), 256, 0, stream>>>(W_o, Wo_t, 2048, 2048);

    // q = (x @ W_q) * 1/sqrt(128)   [softmax scale folded in]
    k_gemm_bt<1><<<dim3(16, 32), 256, 0, stream>>>(xb, Wq_t, qb, nullptr, 4096, 2048, 2048,
                                                   0.08838834764831845f);
    // latent = x @ W_kv_down
    k_gemm_bt<1><<<dim3(4, 32), 256, 0, stream>>>(xb, Wkvd_t, lat, nullptr, 4096, 512, 2048,
                                                  1.0f);
    // kv = latent @ W_kv_up  (also writes kvT = per-head transposed copy; xb is dead now)
    k_gemm_bt<2><<<dim3(16, 32), 256, 0, stream>>>(lat, Wkvu_t, kvb, kvT, 4096, 2048, 512,
                                                   1.0f);
    // flash attention (output in-place over qb)
    k_attn<<<dim3(16, 32), 256, 0, stream>>>(qb, kvb, kvT, qb);
    // out = attn @ W_o  (fp32 output)
    k_gemm_bt<0><<<dim3(16, 32), 256, 0, stream>>>(qb, Wo_t, d_out, nullptr, 4096, 2048, 2048,
                                                   1.0f);
}